// Round 3
// baseline (387.307 us; speedup 1.0000x reference)
//
#include <hip/hip_runtime.h>
#include <limits.h>
#include <math.h>

// CalcImpute: per-row top-16-smallest (stable: lexicographic (value,index))
// over 50000 donors, then masked mean of gathered donor values.
// Wave-global replicated top-16 list; exact running threshold Tv gates the
// stream (candidates ~16*ln(50000/256) ~ 84/row). This round: 64 B/lane/step
// double-buffered stream (4 KB/wave-step, 4 loads in flight) + min-tree gate
// to cut hot-loop VALU and loop overhead. Memory-bound target ~1.64 GB once.

#define K          16
#define NDON       50000
#define NF4        12500      // float4 per row
#define MAIN_START 64         // prologue consumes f4 [0, 64)
#define MAIN_STEPS 48         // 48 steps x 256 f4 (4/lane) -> [64, 12352)
#define TAIL_START 12352      // remaining 148 f4

__device__ __forceinline__ bool lexless(float v1, int i1, float v2, int i2) {
    return (v1 < v2) || ((v1 == v2) && (i1 < i2));
}

__device__ __forceinline__ float nanfix(float v) { return (v != v) ? 1e10f : v; }

// Insert candidate (cv,ci) into the sorted (ascending lex) replicated list.
// (cv,ci) are wave-uniform; all control flow here is wave-uniform.
__device__ __forceinline__ void insert16(float (&vals)[K], int (&idxs)[K],
                                         float cv, int ci) {
    if (!lexless(cv, ci, vals[K - 1], idxs[K - 1])) return;
    bool prev = true;  // cand < vals[15] (guard above)
#pragma unroll
    for (int j = K - 1; j >= 1; --j) {
        const bool up = lexless(cv, ci, vals[j - 1], idxs[j - 1]);
        const float nv = up ? vals[j - 1] : (prev ? cv : vals[j]);
        const int   ni = up ? idxs[j - 1] : (prev ? ci : idxs[j]);
        vals[j] = nv; idxs[j] = ni;
        prev = up;
    }
    if (prev) { vals[0] = cv; idxs[0] = ci; }
}

// compare-exchange for the prologue 4-sort
#define CE(va, ia, vb, ib)                                         \
    {                                                              \
        const bool sw_ = lexless(vb, ib, va, ia);                  \
        const float tv_ = va; const int ti_ = ia;                  \
        va = sw_ ? vb : va; ia = sw_ ? ib : ia;                    \
        vb = sw_ ? tv_ : vb; ib = sw_ ? ti_ : ib;                  \
    }

__global__ void __launch_bounds__(256, 4)
calc_impute_topk(const float* __restrict__ dist,
                 const float* __restrict__ fitX,
                 const int*   __restrict__ mask,
                 float* __restrict__ out,
                 int nrows)
{
    const int gtid = blockIdx.x * blockDim.x + threadIdx.x;
    const int wrow = gtid >> 6;          // one wave per row
    const int lane = threadIdx.x & 63;
    if (wrow >= nrows) return;

    const float4* __restrict__ r4 =
        reinterpret_cast<const float4*>(dist + (size_t)wrow * NDON);

    // ---- Prologue: exact top-16 of the first 256 elements ----
    float4 d = r4[lane];
    float l0 = nanfix(d.x), l1 = nanfix(d.y), l2 = nanfix(d.z), l3 = nanfix(d.w);
    int   j0 = lane * 4, j1 = j0 + 1, j2 = j0 + 2, j3 = j0 + 3;
    CE(l0, j0, l1, j1); CE(l2, j2, l3, j3);
    CE(l0, j0, l2, j2); CE(l1, j1, l3, j3);
    CE(l1, j1, l2, j2);

    float vals[K];
    int   idxs[K];
#pragma unroll
    for (int r = 0; r < K; ++r) {
        float mv = l0; int mi = j0;
#pragma unroll
        for (int m = 32; m >= 1; m >>= 1) {
            const float ov = __shfl_xor(mv, m, 64);
            const int   oi = __shfl_xor(mi, m, 64);
            if (lexless(ov, oi, mv, mi)) { mv = ov; mi = oi; }
        }
        vals[r] = mv; idxs[r] = mi;          // wave-uniform
        if (l0 == mv && j0 == mi) {          // unique winner pops its head
            l0 = l1; j0 = j1; l1 = l2; j1 = j2; l2 = l3; j2 = j3;
            l3 = INFINITY; j3 = INT_MAX;
        }
    }
    float Tv = vals[K - 1];                  // exact running 16th smallest

    // Candidates that pass (x <= Tv) are finite (NaN fails the compare; a
    // NaN's reference value 1e10 > Tv for this data), so no nanfix needed
    // in the hot path.
#define PROC(ve, ie)                                                   \
    {                                                                  \
        unsigned long long bb_ = __ballot((ve) <= Tv);                 \
        while (bb_) {                                                  \
            const int src_ = __builtin_ctzll(bb_); bb_ &= bb_ - 1;     \
            const float cv_ = __shfl((ve), src_, 64);                  \
            const int   ci_ = __shfl((ie), src_, 64);                  \
            insert16(vals, idxs, cv_, ci_);                            \
        }                                                              \
    }

    // ---- Main loop: 4 float4/lane/step, double-buffered ----
    const float4* p0 = r4 + MAIN_START + lane;
    float4 c0 = p0[0], c1 = p0[64], c2 = p0[128], c3 = p0[192];
#pragma unroll 1
    for (int s = 0; s < MAIN_STEPS; ++s) {
        float4 n0, n1, n2, n3;
        const bool more = (s + 1 < MAIN_STEPS);
        if (more) {
            const float4* pn = r4 + MAIN_START + (s + 1) * 256 + lane;
            n0 = pn[0]; n1 = pn[64]; n2 = pn[128]; n3 = pn[192];
        }
        // min-tree gate over the 16 streamed elements (fminf ignores NaN)
        const float m0 = fminf(fminf(c0.x, c0.y), fminf(c0.z, c0.w));
        const float m1 = fminf(fminf(c1.x, c1.y), fminf(c1.z, c1.w));
        const float m2 = fminf(fminf(c2.x, c2.y), fminf(c2.z, c2.w));
        const float m3 = fminf(fminf(c3.x, c3.y), fminf(c3.z, c3.w));
        const float mn = fminf(fminf(m0, m1), fminf(m2, m3));
        if (__any(mn <= Tv)) {
            const int b0 = (MAIN_START + s * 256 + lane) * 4;
            PROC(c0.x, b0 + 0);   PROC(c0.y, b0 + 1);
            PROC(c0.z, b0 + 2);   PROC(c0.w, b0 + 3);
            PROC(c1.x, b0 + 256); PROC(c1.y, b0 + 257);
            PROC(c1.z, b0 + 258); PROC(c1.w, b0 + 259);
            PROC(c2.x, b0 + 512); PROC(c2.y, b0 + 513);
            PROC(c2.z, b0 + 514); PROC(c2.w, b0 + 515);
            PROC(c3.x, b0 + 768); PROC(c3.y, b0 + 769);
            PROC(c3.z, b0 + 770); PROC(c3.w, b0 + 771);
            Tv = vals[K - 1];
        }
        c0 = n0; c1 = n1; c2 = n2; c3 = n3;
    }

    // ---- Tail: 148 remaining float4 (3 masked rounds of 64) ----
#pragma unroll 1
    for (int t = 0; t < 3; ++t) {
        const int f4i = TAIL_START + t * 64 + lane;
        float4 e;
        if (f4i < NF4) {
            e = r4[f4i];
        } else {
            e.x = e.y = e.z = e.w = INFINITY;
        }
        const int b0 = f4i * 4;
        PROC(e.x, b0 + 0); PROC(e.y, b0 + 1);
        PROC(e.z, b0 + 2); PROC(e.w, b0 + 3);
    }
#undef PROC

    // ---- Epilogue: list is the sorted global top-16, replicated ----
    float s_w = 0.0f, s_wx = 0.0f;
#pragma unroll
    for (int r = 0; r < K; ++r) {
        const int mi = idxs[r];                       // wave-uniform
        const float w = 1.0f - (float)mask[mi];
        s_w  += w;
        s_wx += w * fitX[mi];
    }
    if (lane == 0) {
        out[wrow] = s_wx / ((s_w == 0.0f) ? 1.0f : s_w);
    }
}

extern "C" void kernel_launch(void* const* d_in, const int* in_sizes, int n_in,
                              void* d_out, int out_size, void* d_ws, size_t ws_size,
                              hipStream_t stream) {
    const float* dist = (const float*)d_in[0];
    // d_in[1] is n_neighbors (==16, fixed; K hardcoded)
    const float* fitX = (const float*)d_in[2];
    const int*   mask = (const int*)d_in[3];
    float* out = (float*)d_out;

    const int nrows = out_size;                 // 8192
    const int threads = 256;                    // 4 waves/block, 1 row/wave
    const int blocks = (nrows * 64 + threads - 1) / threads;

    calc_impute_topk<<<blocks, threads, 0, stream>>>(dist, fitX, mask, out, nrows);
}